// Round 1
// baseline (455.968 us; speedup 1.0000x reference)
//
#include <hip/hip_runtime.h>
#include <math.h>

// Problem shape (fixed by the harness): logits [1, T, U, D]
#define TDIM 2000
#define UDIM 32
#define DDIM 4096
#define DEPTH 8   // software-pipeline depth for the DP kernel's emit/blk loads

// ---------------------------------------------------------------------------
// Kernel 1: per (t,u) row of D=4096 logits, compute
//   blk[t,u]  = log_softmax(row)[0]       = (x[0]      - max) - log(sum exp(x - max))
//   emit[t,u] = log_softmax(row)[tgt[u]]  = (x[tgt[u]] - max) - log(sum exp(x - max))
// One block per row; 256 threads x 16 floats (4x float4, fully coalesced).
// ---------------------------------------------------------------------------
__global__ __launch_bounds__(256) void k_rowstats(
    const float* __restrict__ logits, const int* __restrict__ tgt,
    float* __restrict__ emit, float* __restrict__ blk)
{
    const int r = blockIdx.x;              // r = t*UDIM + u
    const int u = r & (UDIM - 1);
    const float* row = logits + (size_t)r * DDIM;
    const float4* row4 = reinterpret_cast<const float4*>(row);
    const int tid = threadIdx.x;

    float4 x0 = row4[tid];
    float4 x1 = row4[tid + 256];
    float4 x2 = row4[tid + 512];
    float4 x3 = row4[tid + 768];

    float m = fmaxf(fmaxf(fmaxf(x0.x, x0.y), fmaxf(x0.z, x0.w)),
               fmaxf(fmaxf(fmaxf(x1.x, x1.y), fmaxf(x1.z, x1.w)),
                fmaxf(fmaxf(fmaxf(x2.x, x2.y), fmaxf(x2.z, x2.w)),
                      fmaxf(fmaxf(x3.x, x3.y), fmaxf(x3.z, x3.w)))));
    #pragma unroll
    for (int off = 32; off > 0; off >>= 1)
        m = fmaxf(m, __shfl_xor(m, off));

    __shared__ float redm[4];
    __shared__ float reds[4];
    const int wid = tid >> 6, lane = tid & 63;
    if (lane == 0) redm[wid] = m;
    __syncthreads();
    m = fmaxf(fmaxf(redm[0], redm[1]), fmaxf(redm[2], redm[3]));

    float s = 0.f;
    s += expf(x0.x - m) + expf(x0.y - m) + expf(x0.z - m) + expf(x0.w - m);
    s += expf(x1.x - m) + expf(x1.y - m) + expf(x1.z - m) + expf(x1.w - m);
    s += expf(x2.x - m) + expf(x2.y - m) + expf(x2.z - m) + expf(x2.w - m);
    s += expf(x3.x - m) + expf(x3.y - m) + expf(x3.z - m) + expf(x3.w - m);
    #pragma unroll
    for (int off = 32; off > 0; off >>= 1)
        s += __shfl_xor(s, off);
    if (lane == 0) reds[wid] = s;
    __syncthreads();

    if (tid == 0) {
        float tot = (reds[0] + reds[1]) + (reds[2] + reds[3]);
        float l = logf(tot);
        float xb = x0.x;            // row[0] — tid 0 already holds it
        float xt = row[tgt[u]];     // gather; L1/L2 hit (block just read the row)
        blk[r]  = (xb - m) - l;
        emit[r] = (xt - m) - l;
    }
}

// ---------------------------------------------------------------------------
// Kernel 2: anti-diagonal wavefront DP, single wave. Lane u computes cell
// (t = n - u, u) at step n, using its own previous value (alpha[t-1,u]) and
// lane u-1's previous value (alpha[t,u-1]) via __shfl_up. Reproduces the
// reference's sequential rounding and ">=" (prefer-blank) tie-break exactly.
// Loads of blk/emit depend only on n — software-pipelined DEPTH ahead.
// ---------------------------------------------------------------------------
__global__ __launch_bounds__(64) void k_dp(
    const float* __restrict__ emit, const float* __restrict__ blk,
    const int* __restrict__ tlenp,
    float* __restrict__ a_raw,      // ws: alpha[t, tl]  (length T)
    float* __restrict__ out_st,     // d_out + 1 + T
    float* __restrict__ out_to)     // d_out + 1 + 2T
{
    const int u  = (int)threadIdx.x;        // lanes 0..63; only u < UDIM meaningful
    const int tl = tlenp[0];                 // = 31
    const int nstep = TDIM + tl;             // steps n = 0 .. nstep-1 cover t=0..T-1 at lane tl
    const int npad  = (nstep + DEPTH - 1) & ~(DEPTH - 1);

    float a = 0.f, s = 0.f, tt = 0.f;        // alpha / start / total of cell (t-1, u)
    float bp[DEPTH], ep[DEPTH];

    auto issue = [&](int n, float& bpv, float& epv) {
        int t  = n - u;
        int ib = (t - 1) * UDIM + u;                 // blk[t-1, u]   (stay path)
        ib = min(max(ib, 0), TDIM * UDIM - 1);
        bpv = blk[ib];
        int ie = t * UDIM + (u - 1);                 // emit[t, u-1]  (emit path)
        ie = min(max(ie, 0), TDIM * UDIM - 1);
        epv = emit[ie];
    };

    #pragma unroll
    for (int k = 0; k < DEPTH; ++k) issue(k, bp[k], ep[k]);

    for (int n0 = 0; n0 < npad; n0 += DEPTH) {
        #pragma unroll
        for (int j = 0; j < DEPTH; ++j) {
            const int n = n0 + j;
            const int t = n - u;

            float aL = __shfl_up(a, 1);
            float sL = __shfl_up(s, 1);
            float tL = __shfl_up(tt, 1);

            float fla = (t >= 1) ? (a + bp[j]) : -INFINITY;  // stay (blank) path
            float fd  = aL + ep[j];                          // emit (label) path

            issue(n + DEPTH, bp[j], ep[j]);   // prefetch; addresses independent of DP chain

            bool  left = (fla >= fd);         // tie prefers blank, matching reference
            float na = left ? fla : fd;
            float ns = left ? s   : sL;
            float nt = (left ? tt : tL) + 1.0f;
            if (u == 0) { na = 0.f; ns = (float)t; nt = 1.f; }   // alpha[t,0]=0, start=t, total=1
            a = na; s = ns; tt = nt;

            if (u == tl && t >= 0 && t < TDIM) {
                a_raw[t]  = a;            // alpha[t, tl]
                out_st[t] = s;            // start[t, tl]
                out_to[t] = tt + 1.0f;    // total[t, tl] + 1
            }
        }
    }
}

// ---------------------------------------------------------------------------
// Kernel 3: la[t] = alpha[t,tl] + blk[t,tl]; also write scalar la[T-1] at out[0].
// ---------------------------------------------------------------------------
__global__ void k_finalize(const float* __restrict__ a_raw,
                           const float* __restrict__ blk,
                           const int* __restrict__ tlenp,
                           float* __restrict__ out)
{
    int t = blockIdx.x * blockDim.x + threadIdx.x;
    if (t >= TDIM) return;
    int tl = tlenp[0];
    float la = a_raw[t] + blk[t * UDIM + tl];
    out[1 + t] = la;
    if (t == TDIM - 1) out[0] = la;
}

extern "C" void kernel_launch(void* const* d_in, const int* in_sizes, int n_in,
                              void* d_out, int out_size, void* d_ws, size_t ws_size,
                              hipStream_t stream)
{
    const float* logits      = (const float*)d_in[0];
    const int*   targets     = (const int*)d_in[1];
    const int*   target_lens = (const int*)d_in[3];
    float* out = (float*)d_out;

    // ws layout: emit[T*U] | blk[T*U] | a_raw[T]   (520 KB total)
    float* emit  = (float*)d_ws;
    float* blk   = emit + TDIM * UDIM;
    float* a_raw = blk  + TDIM * UDIM;

    k_rowstats<<<TDIM * UDIM, 256, 0, stream>>>(logits, targets, emit, blk);
    k_dp<<<1, 64, 0, stream>>>(emit, blk, target_lens, a_raw,
                               out + 1 + TDIM, out + 1 + 2 * TDIM);
    k_finalize<<<(TDIM + 255) / 256, 256, 0, stream>>>(a_raw, blk, target_lens, out);
}